// Round 3
// baseline (1827.526 us; speedup 1.0000x reference)
//
#include <hip/hip_runtime.h>

#define HID   64
#define ENC_T 20
#define DEC_T 30
#define HS    72   // sH row stride in bf16 elements: 144B, 16B-aligned, bank-staggered

typedef __bf16 bf16x8 __attribute__((ext_vector_type(8)));
typedef float  f32x4  __attribute__((ext_vector_type(4)));
typedef float  f32x2  __attribute__((ext_vector_type(2)));
typedef unsigned short u16x8 __attribute__((ext_vector_type(8)));
typedef unsigned short ushort_t;
typedef unsigned int   uint_t;

#if __has_builtin(__builtin_amdgcn_exp2f)
#define EXP2F(x) __builtin_amdgcn_exp2f(x)
#else
#define EXP2F(x) exp2f(x)
#endif
#if __has_builtin(__builtin_amdgcn_rcpf)
#define RCPF(x) __builtin_amdgcn_rcpf(x)
#else
#define RCPF(x) (1.0f / (x))
#endif

#define L2E 1.4426950408889634f

__device__ __forceinline__ float bf2f(ushort_t u) {
    union { uint_t i; float f; } v; v.i = ((uint_t)u) << 16; return v.f;
}
// fp32 -> bf16 RNE via native cast (v_cvt path on gfx950)
__device__ __forceinline__ ushort_t f2bf(float f) {
    __bf16 b = (__bf16)f;
    union { __bf16 b; ushort_t u; } v; v.b = b; return v.u;
}
__device__ __forceinline__ float bfround(float f) {   // value rounded to bf16
    __bf16 b = (__bf16)f; return (float)b;
}

// inputs pre-scaled by log2e: sigmoid(x) where arg = x*log2e
__device__ __forceinline__ float fsig2(float xs) {
    float e = EXP2F(-xs);
    return RCPF(1.0f + e);
}
// inputs pre-scaled by 2*log2e: tanh(x) where arg = 2x*log2e
__device__ __forceinline__ float ftanh2(float xs) {
    float e = EXP2F(-xs);
    return fmaf(2.0f, RCPF(1.0f + e), -1.0f);
}
// unscaled tanh (for c_new)
__device__ __forceinline__ float ftanh_(float x) {
    float e = EXP2F(x * (-2.0f * L2E));
    return fmaf(2.0f, RCPF(1.0f + e), -1.0f);
}

struct bfpair { bf16x8 hi, lo; };

// Split 8 consecutive fp32 (scaled by s) into bf16 hi + lo fragments
__device__ __forceinline__ bfpair split8s(const float* __restrict__ p, float s) {
    u16x8 h, l;
    #pragma unroll
    for (int u = 0; u < 8; ++u) {
        float f = p[u] * s;
        float fh = bfround(f);
        h[u] = f2bf(f);            // same rounding as fh
        l[u] = f2bf(f - fh);
    }
    bfpair r;
    __builtin_memcpy(&r.hi, &h, 16);
    __builtin_memcpy(&r.lo, &l, 16);
    return r;
}

__global__ __launch_bounds__(256, 5)
void lstm_seq2seq(const float* __restrict__ traj,
                  const float* __restrict__ WihE, const float* __restrict__ WhhE,
                  const float* __restrict__ bihE, const float* __restrict__ bhhE,
                  const float* __restrict__ WihD, const float* __restrict__ WhhD,
                  const float* __restrict__ bihD, const float* __restrict__ bhhD,
                  const float* __restrict__ Wpos, const float* __restrict__ bpos,
                  float* __restrict__ out)
{
    __shared__ __align__(16) ushort_t sHh[2][16 * HS];  // h hi, double buffer
    __shared__ __align__(16) ushort_t sHl[2][16 * HS];  // h lo
    __shared__ __align__(16) float    sX[16 * ENC_T * 2];  // traj tile fp32

    const int tid  = threadIdx.x;
    const int w    = tid >> 6;      // wave 0..3 -> gate-unit tile (units 16w..16w+15)
    const int lane = tid & 63;
    const int col  = lane & 15;     // MFMA col (n for B / C; m for A)
    const int quad = lane >> 4;
    const int wg   = blockIdx.x;    // 16 batch rows per workgroup

    // per-gate pre-scale: i,f,o by log2e; g by 2*log2e (tanh form)
    const float gsc[4] = { L2E, L2E, 2.0f * L2E, L2E };

    // ---- stage trajectory tile: 640 contiguous floats ----
    {
        const float* src = traj + (size_t)wg * (16 * ENC_T * 2);
        #pragma unroll
        for (int i = 0; i < 3; ++i) {
            int idx = tid + i * 256;
            if (idx < 640) sX[idx] = src[idx];
        }
    }
    // ---- zero h buffer 0 ----
    {
        uint_t* hz0 = (uint_t*)&sHh[0][0];
        uint_t* hz1 = (uint_t*)&sHl[0][0];
        for (int j = tid; j < 16 * HS / 2; j += 256) { hz0[j] = 0; hz1[j] = 0; }
    }

    // ---- per-lane encoder constants (fp32, pre-scaled): gate g = 64j + 16w + col ----
    float wi0[4], wi1[4], bE[4];
    #pragma unroll
    for (int j = 0; j < 4; ++j) {
        int g = 64 * j + 16 * w + col;
        wi0[j] = WihE[g * 2 + 0] * gsc[j];
        wi1[j] = WihE[g * 2 + 1] * gsc[j];
        bE[j]  = (bihE[g] + bhhE[g]) * gsc[j];
    }

    // ---- encoder W_hh fragments direct global -> registers (hi/lo, pre-scaled) ----
    bfpair bw[4][2];
    #pragma unroll
    for (int j = 0; j < 4; ++j) {
        int g = 64 * j + 16 * w + col;
        #pragma unroll
        for (int kb = 0; kb < 2; ++kb)
            bw[j][kb] = split8s(WhhE + g * 64 + kb * 32 + quad * 8, gsc[j]);
    }

    float c[4] = {0.f, 0.f, 0.f, 0.f};   // c-state rows quad*4+r, unit 16w+col
    int buf = 0;

    __syncthreads();

    // =========================== ENCODER ===========================
    for (int t = 0; t < ENC_T; ++t) {
        f32x4 acc[4];
        #pragma unroll
        for (int r = 0; r < 4; ++r) {
            f32x2 xp = *(const f32x2*)&sX[(quad * 4 + r) * (ENC_T * 2) + 2 * t];
            #pragma unroll
            for (int j = 0; j < 4; ++j)
                acc[j][r] = fmaf(wi1[j], xp[1], fmaf(wi0[j], xp[0], bE[j]));
        }
        bf16x8 a0h = *(const bf16x8*)&sHh[buf][col * HS +  0 + quad * 8];
        bf16x8 a1h = *(const bf16x8*)&sHh[buf][col * HS + 32 + quad * 8];
        bf16x8 a0l = *(const bf16x8*)&sHl[buf][col * HS +  0 + quad * 8];
        bf16x8 a1l = *(const bf16x8*)&sHl[buf][col * HS + 32 + quad * 8];
        #pragma unroll
        for (int j = 0; j < 4; ++j) {
            acc[j] = __builtin_amdgcn_mfma_f32_16x16x32_bf16(a0l, bw[j][0].hi, acc[j], 0, 0, 0);
            acc[j] = __builtin_amdgcn_mfma_f32_16x16x32_bf16(a1l, bw[j][1].hi, acc[j], 0, 0, 0);
            acc[j] = __builtin_amdgcn_mfma_f32_16x16x32_bf16(a0h, bw[j][0].lo, acc[j], 0, 0, 0);
            acc[j] = __builtin_amdgcn_mfma_f32_16x16x32_bf16(a1h, bw[j][1].lo, acc[j], 0, 0, 0);
            acc[j] = __builtin_amdgcn_mfma_f32_16x16x32_bf16(a0h, bw[j][0].hi, acc[j], 0, 0, 0);
            acc[j] = __builtin_amdgcn_mfma_f32_16x16x32_bf16(a1h, bw[j][1].hi, acc[j], 0, 0, 0);
        }
        #pragma unroll
        for (int r = 0; r < 4; ++r) {
            float ig = fsig2(acc[0][r]);
            float fg = fsig2(acc[1][r]);
            float gg = ftanh2(acc[2][r]);
            float og = fsig2(acc[3][r]);
            float cn = fmaf(fg, c[r], ig * gg);
            c[r] = cn;
            float hn = og * ftanh_(cn);
            int idx = (quad * 4 + r) * HS + 16 * w + col;
            float fh = bfround(hn);
            sHh[buf ^ 1][idx] = f2bf(hn);
            sHl[buf ^ 1][idx] = f2bf(hn - fh);
        }
        __syncthreads();
        buf ^= 1;
    }

    // ---- decoder combined weights Wc = (W_ih_dec + W_hh_dec)*scale (hi/lo split) ----
    float bD[4];
    #pragma unroll
    for (int j = 0; j < 4; ++j) {
        int g = 64 * j + 16 * w + col;
        bD[j] = (bihD[g] + bhhD[g]) * gsc[j];
        #pragma unroll
        for (int kb = 0; kb < 2; ++kb) {
            int off = g * 64 + kb * 32 + quad * 8;
            float tmp[8];
            #pragma unroll
            for (int u = 0; u < 8; ++u) tmp[u] = WihD[off + u] + WhhD[off + u];
            bw[j][kb] = split8s(tmp, gsc[j]);
        }
    }

    // projection constants: lane = quad*16 + pcomp*8 + pseg ; row = 4w + quad
    const int prow  = 4 * w + quad;
    const int pcomp = (lane >> 3) & 1;
    const int pseg  = lane & 7;
    float wp[8];
    #pragma unroll
    for (int u = 0; u < 8; ++u) wp[u] = Wpos[pcomp * 64 + pseg * 8 + u];
    const float bp = bpos[pcomp];

    // =========================== DECODER ===========================
    for (int t = 0; t < DEC_T; ++t) {
        f32x4 acc[4];
        #pragma unroll
        for (int j = 0; j < 4; ++j) {
            acc[j][0] = bD[j]; acc[j][1] = bD[j]; acc[j][2] = bD[j]; acc[j][3] = bD[j];
        }
        bf16x8 a0h = *(const bf16x8*)&sHh[buf][col * HS +  0 + quad * 8];
        bf16x8 a1h = *(const bf16x8*)&sHh[buf][col * HS + 32 + quad * 8];
        bf16x8 a0l = *(const bf16x8*)&sHl[buf][col * HS +  0 + quad * 8];
        bf16x8 a1l = *(const bf16x8*)&sHl[buf][col * HS + 32 + quad * 8];
        #pragma unroll
        for (int j = 0; j < 4; ++j) {
            acc[j] = __builtin_amdgcn_mfma_f32_16x16x32_bf16(a0l, bw[j][0].hi, acc[j], 0, 0, 0);
            acc[j] = __builtin_amdgcn_mfma_f32_16x16x32_bf16(a1l, bw[j][1].hi, acc[j], 0, 0, 0);
            acc[j] = __builtin_amdgcn_mfma_f32_16x16x32_bf16(a0h, bw[j][0].lo, acc[j], 0, 0, 0);
            acc[j] = __builtin_amdgcn_mfma_f32_16x16x32_bf16(a1h, bw[j][1].lo, acc[j], 0, 0, 0);
            acc[j] = __builtin_amdgcn_mfma_f32_16x16x32_bf16(a0h, bw[j][0].hi, acc[j], 0, 0, 0);
            acc[j] = __builtin_amdgcn_mfma_f32_16x16x32_bf16(a1h, bw[j][1].hi, acc[j], 0, 0, 0);
        }
        #pragma unroll
        for (int r = 0; r < 4; ++r) {
            float ig = fsig2(acc[0][r]);
            float fg = fsig2(acc[1][r]);
            float gg = ftanh2(acc[2][r]);
            float og = fsig2(acc[3][r]);
            float cn = fmaf(fg, c[r], ig * gg);
            c[r] = cn;
            float hn = og * ftanh_(cn);
            int idx = (quad * 4 + r) * HS + 16 * w + col;
            float fh = bfround(hn);
            sHh[buf ^ 1][idx] = f2bf(hn);
            sHl[buf ^ 1][idx] = f2bf(hn - fh);
        }
        __syncthreads();
        buf ^= 1;
        // out_t = h_{t+1} @ Wpos^T + b_pos ; h_{t+1} now in sH*[buf].
        {
            u16x8 hvh = *(const u16x8*)&sHh[buf][prow * HS + pseg * 8];
            u16x8 hvl = *(const u16x8*)&sHl[buf][prow * HS + pseg * 8];
            float p = 0.f;
            #pragma unroll
            for (int u = 0; u < 8; ++u)
                p = fmaf(bf2f(hvh[u]) + bf2f(hvl[u]), wp[u], p);
            p += __shfl_xor(p, 1, 64);
            p += __shfl_xor(p, 2, 64);
            p += __shfl_xor(p, 4, 64);
            if (pseg == 0)
                out[(size_t)(wg * 16 + prow) * (DEC_T * 2) + t * 2 + pcomp] = p + bp;
        }
    }
}

extern "C" void kernel_launch(void* const* d_in, const int* in_sizes, int n_in,
                              void* d_out, int out_size, void* d_ws, size_t ws_size,
                              hipStream_t stream) {
    const float* traj = (const float*)d_in[0];
    const float* WihE = (const float*)d_in[1];
    const float* WhhE = (const float*)d_in[2];
    const float* bihE = (const float*)d_in[3];
    const float* bhhE = (const float*)d_in[4];
    const float* WihD = (const float*)d_in[5];
    const float* WhhD = (const float*)d_in[6];
    const float* bihD = (const float*)d_in[7];
    const float* bhhD = (const float*)d_in[8];
    const float* Wpos = (const float*)d_in[9];
    const float* bpos = (const float*)d_in[10];
    float* out = (float*)d_out;

    const int B = in_sizes[0] / (ENC_T * 2);   // 65536
    const int grid = B / 16;                   // 4096 workgroups, 16 rows each

    lstm_seq2seq<<<grid, 256, 0, stream>>>(traj, WihE, WhhE, bihE, bhhE,
                                           WihD, WhhD, bihD, bhhD, Wpos, bpos, out);
}

// Round 4
// 435.270 us; speedup vs baseline: 4.1986x; 4.1986x over previous
//
#include <hip/hip_runtime.h>

#define HID   64
#define ENC_T 20
#define DEC_T 30
#define HS    72   // sH row stride in bf16 elems: 144B = 16B-aligned
#define PS    36   // sP row stride in dwords: [16 rows][2 comp][16 partials + 4 pad]

typedef __bf16 bf16x8 __attribute__((ext_vector_type(8)));
typedef float  f32x4  __attribute__((ext_vector_type(4)));
typedef float  f32x2  __attribute__((ext_vector_type(2)));
typedef unsigned short u16x4 __attribute__((ext_vector_type(4)));
typedef unsigned short ushort_t;
typedef unsigned int   uint_t;

#if __has_builtin(__builtin_amdgcn_exp2f)
#define EXP2F(x) __builtin_amdgcn_exp2f(x)
#else
#define EXP2F(x) exp2f(x)
#endif
#if __has_builtin(__builtin_amdgcn_rcpf)
#define RCPF(x) __builtin_amdgcn_rcpf(x)
#else
#define RCPF(x) (1.0f / (x))
#endif

#define L2E 1.4426950408889634f

__device__ __forceinline__ ushort_t f2bf(float f) {
    __bf16 b = (__bf16)f;
    union { __bf16 b; ushort_t u; } v; v.b = b; return v.u;
}
__device__ __forceinline__ float bfround(float f) {
    __bf16 b = (__bf16)f; return (float)b;
}
// arg pre-scaled by log2e
__device__ __forceinline__ float fsig2(float xs) {
    float e = EXP2F(-xs);
    return RCPF(1.0f + e);
}
// arg pre-scaled by 2*log2e
__device__ __forceinline__ float ftanh2(float xs) {
    float e = EXP2F(-xs);
    return fmaf(2.0f, RCPF(1.0f + e), -1.0f);
}
// unscaled
__device__ __forceinline__ float ftanh_(float x) {
    float e = EXP2F(x * (-2.0f * L2E));
    return fmaf(2.0f, RCPF(1.0f + e), -1.0f);
}

struct bfpair { bf16x8 hi, lo; };

// Split 8 consecutive fp32 (scaled by s) into bf16 hi + lo fragments
__device__ __forceinline__ bfpair split8s(const float* __restrict__ p, float s) {
    unsigned short h[8], l[8];
    #pragma unroll
    for (int u = 0; u < 8; ++u) {
        float f = p[u] * s;
        float fh = bfround(f);
        h[u] = f2bf(f);
        l[u] = f2bf(f - fh);
    }
    bfpair r;
    __builtin_memcpy(&r.hi, h, 16);
    __builtin_memcpy(&r.lo, l, 16);
    return r;
}

__global__ __launch_bounds__(256, 3)
void lstm_seq2seq(const float* __restrict__ traj,
                  const float* __restrict__ WihE, const float* __restrict__ WhhE,
                  const float* __restrict__ bihE, const float* __restrict__ bhhE,
                  const float* __restrict__ WihD, const float* __restrict__ WhhD,
                  const float* __restrict__ bihD, const float* __restrict__ bhhD,
                  const float* __restrict__ Wpos, const float* __restrict__ bpos,
                  float* __restrict__ out)
{
    __shared__ __align__(16) ushort_t sHh[2][16 * HS];   // h hi [row][unit]
    __shared__ __align__(16) ushort_t sHl[2][16 * HS];   // h lo
    __shared__ __align__(16) float    sX[16 * ENC_T * 2];
    __shared__ __align__(16) float    sP[2][16 * PS];    // projection partials

    const int tid  = threadIdx.x;
    const int w    = tid >> 6;      // wave -> unit tile (units 16w..16w+15)
    const int lane = tid & 63;
    const int col  = lane & 15;     // n-index: BATCH ROW for this lane
    const int quad = lane >> 4;     // m-quad: units 16w + quad*4 + r
    const int wg   = blockIdx.x;

    const float gsc[4] = { L2E, L2E, 2.0f * L2E, L2E };  // i,f,g(tanh),o pre-scales

    // ---- stage trajectory tile: 640 contiguous floats ----
    {
        const float* src = traj + (size_t)wg * (16 * ENC_T * 2);
        #pragma unroll
        for (int i = 0; i < 3; ++i) {
            int idx = tid + i * 256;
            if (idx < 640) sX[idx] = src[idx];
        }
    }
    // ---- zero h buffer 0 ----
    {
        uint_t* hz0 = (uint_t*)&sHh[0][0];
        uint_t* hz1 = (uint_t*)&sHl[0][0];
        for (int j = tid; j < 16 * HS / 2; j += 256) { hz0[j] = 0; hz1[j] = 0; }
    }

    // ---- encoder per-lane constants: gate j, unit u16 = quad*4 + r in tile w ----
    // global gate row g = 64*j + 16*w + quad*4 + r
    float wi0[4][4], wi1[4][4], bE[4][4];
    #pragma unroll
    for (int j = 0; j < 4; ++j)
        #pragma unroll
        for (int r = 0; r < 4; ++r) {
            int g = 64 * j + 16 * w + quad * 4 + r;
            wi0[j][r] = WihE[g * 2 + 0] * gsc[j];
            wi1[j][r] = WihE[g * 2 + 1] * gsc[j];
            bE[j][r]  = (bihE[g] + bhhE[g]) * gsc[j];
        }

    // ---- encoder W_hh A-fragments: A[m=col][k=kb*32+quad*8+u] ----
    bfpair bw[4][2];
    #pragma unroll
    for (int j = 0; j < 4; ++j) {
        int g = 64 * j + 16 * w + col;
        #pragma unroll
        for (int kb = 0; kb < 2; ++kb)
            bw[j][kb] = split8s(WhhE + g * 64 + kb * 32 + quad * 8, gsc[j]);
    }

    float c[4] = {0.f, 0.f, 0.f, 0.f};   // c for (row=col, unit=16w+quad*4+r)
    int buf = 0;

    __syncthreads();

    // =========================== ENCODER ===========================
    for (int t = 0; t < ENC_T; ++t) {
        f32x4 acc[4];
        {
            f32x2 xp = *(const f32x2*)&sX[col * (ENC_T * 2) + 2 * t];
            #pragma unroll
            for (int j = 0; j < 4; ++j)
                #pragma unroll
                for (int r = 0; r < 4; ++r)
                    acc[j][r] = fmaf(wi1[j][r], xp[1], fmaf(wi0[j][r], xp[0], bE[j][r]));
        }
        // B-frags: h rows, B[n=col][k]
        bf16x8 b0h = *(const bf16x8*)&sHh[buf][col * HS +  0 + quad * 8];
        bf16x8 b1h = *(const bf16x8*)&sHh[buf][col * HS + 32 + quad * 8];
        bf16x8 b0l = *(const bf16x8*)&sHl[buf][col * HS +  0 + quad * 8];
        bf16x8 b1l = *(const bf16x8*)&sHl[buf][col * HS + 32 + quad * 8];
        #pragma unroll
        for (int j = 0; j < 4; ++j) {
            acc[j] = __builtin_amdgcn_mfma_f32_16x16x32_bf16(bw[j][0].hi, b0l, acc[j], 0, 0, 0);
            acc[j] = __builtin_amdgcn_mfma_f32_16x16x32_bf16(bw[j][1].hi, b1l, acc[j], 0, 0, 0);
            acc[j] = __builtin_amdgcn_mfma_f32_16x16x32_bf16(bw[j][0].lo, b0h, acc[j], 0, 0, 0);
            acc[j] = __builtin_amdgcn_mfma_f32_16x16x32_bf16(bw[j][1].lo, b1h, acc[j], 0, 0, 0);
            acc[j] = __builtin_amdgcn_mfma_f32_16x16x32_bf16(bw[j][0].hi, b0h, acc[j], 0, 0, 0);
            acc[j] = __builtin_amdgcn_mfma_f32_16x16x32_bf16(bw[j][1].hi, b1h, acc[j], 0, 0, 0);
        }
        // elementwise: acc[j][r] = gate j for (row=col, unit=16w+quad*4+r)
        u16x4 hh, hl;
        #pragma unroll
        for (int r = 0; r < 4; ++r) {
            float ig = fsig2(acc[0][r]);
            float fg = fsig2(acc[1][r]);
            float gg = ftanh2(acc[2][r]);
            float og = fsig2(acc[3][r]);
            float cn = fmaf(fg, c[r], ig * gg);
            c[r] = cn;
            float hn = og * ftanh_(cn);
            float fh = bfround(hn);
            hh[r] = f2bf(hn);
            hl[r] = f2bf(hn - fh);
        }
        *(u16x4*)&sHh[buf ^ 1][col * HS + 16 * w + quad * 4] = hh;
        *(u16x4*)&sHl[buf ^ 1][col * HS + 16 * w + quad * 4] = hl;
        __syncthreads();
        buf ^= 1;
    }

    // ---- decoder combined weights Wc = (W_ih_dec + W_hh_dec)*scale ----
    float bD[4][4];
    #pragma unroll
    for (int j = 0; j < 4; ++j) {
        #pragma unroll
        for (int r = 0; r < 4; ++r) {
            int g = 64 * j + 16 * w + quad * 4 + r;
            bD[j][r] = (bihD[g] + bhhD[g]) * gsc[j];
        }
        int g = 64 * j + 16 * w + col;
        #pragma unroll
        for (int kb = 0; kb < 2; ++kb) {
            int off = g * 64 + kb * 32 + quad * 8;
            float tmp[8];
            #pragma unroll
            for (int u = 0; u < 8; ++u) tmp[u] = WihD[off + u] + WhhD[off + u];
            bw[j][kb] = split8s(tmp, gsc[j]);
        }
    }

    // projection constants: this lane's 4 units
    float wpA[4], wpB[4];
    #pragma unroll
    for (int r = 0; r < 4; ++r) {
        int u = 16 * w + quad * 4 + r;
        wpA[r] = Wpos[u];          // comp 0
        wpB[r] = Wpos[64 + u];     // comp 1
    }
    // wave-0 reducer constants
    const int prow  = lane & 15;
    const int pcomp = (lane >> 4) & 1;
    const float bp  = bpos[pcomp];

    // =========================== DECODER ===========================
    for (int t = 0; t < DEC_T; ++t) {
        f32x4 acc[4];
        #pragma unroll
        for (int j = 0; j < 4; ++j)
            #pragma unroll
            for (int r = 0; r < 4; ++r)
                acc[j][r] = bD[j][r];
        bf16x8 b0h = *(const bf16x8*)&sHh[buf][col * HS +  0 + quad * 8];
        bf16x8 b1h = *(const bf16x8*)&sHh[buf][col * HS + 32 + quad * 8];
        bf16x8 b0l = *(const bf16x8*)&sHl[buf][col * HS +  0 + quad * 8];
        bf16x8 b1l = *(const bf16x8*)&sHl[buf][col * HS + 32 + quad * 8];
        #pragma unroll
        for (int j = 0; j < 4; ++j) {
            acc[j] = __builtin_amdgcn_mfma_f32_16x16x32_bf16(bw[j][0].hi, b0l, acc[j], 0, 0, 0);
            acc[j] = __builtin_amdgcn_mfma_f32_16x16x32_bf16(bw[j][1].hi, b1l, acc[j], 0, 0, 0);
            acc[j] = __builtin_amdgcn_mfma_f32_16x16x32_bf16(bw[j][0].lo, b0h, acc[j], 0, 0, 0);
            acc[j] = __builtin_amdgcn_mfma_f32_16x16x32_bf16(bw[j][1].lo, b1h, acc[j], 0, 0, 0);
            acc[j] = __builtin_amdgcn_mfma_f32_16x16x32_bf16(bw[j][0].hi, b0h, acc[j], 0, 0, 0);
            acc[j] = __builtin_amdgcn_mfma_f32_16x16x32_bf16(bw[j][1].hi, b1h, acc[j], 0, 0, 0);
        }
        u16x4 hh, hl;
        float p0 = 0.f, p1 = 0.f;
        #pragma unroll
        for (int r = 0; r < 4; ++r) {
            float ig = fsig2(acc[0][r]);
            float fg = fsig2(acc[1][r]);
            float gg = ftanh2(acc[2][r]);
            float og = fsig2(acc[3][r]);
            float cn = fmaf(fg, c[r], ig * gg);
            c[r] = cn;
            float hn = og * ftanh_(cn);
            p0 = fmaf(hn, wpA[r], p0);
            p1 = fmaf(hn, wpB[r], p1);
            float fh = bfround(hn);
            hh[r] = f2bf(hn);
            hl[r] = f2bf(hn - fh);
        }
        *(u16x4*)&sHh[buf ^ 1][col * HS + 16 * w + quad * 4] = hh;
        *(u16x4*)&sHl[buf ^ 1][col * HS + 16 * w + quad * 4] = hl;
        // projection partials for h_{t+1}: 16 per (row, comp)
        sP[buf ^ 1][col * PS + 0  + (w * 4 + quad)] = p0;
        sP[buf ^ 1][col * PS + 16 + (w * 4 + quad)] = p1;
        __syncthreads();
        buf ^= 1;
        // wave 0 reduces partials for this step's output (sP[buf] stable until
        // after the NEXT barrier, which wave 0 can't pass before these reads)
        if (w == 0 && lane < 32) {
            const float* pp = &sP[buf][prow * PS + pcomp * 16];
            f32x4 v0 = *(const f32x4*)(pp + 0);
            f32x4 v1 = *(const f32x4*)(pp + 4);
            f32x4 v2 = *(const f32x4*)(pp + 8);
            f32x4 v3 = *(const f32x4*)(pp + 12);
            f32x4 s = (v0 + v1) + (v2 + v3);
            float p = (s[0] + s[1]) + (s[2] + s[3]) + bp;
            out[(size_t)(wg * 16 + prow) * (DEC_T * 2) + t * 2 + pcomp] = p;
        }
    }
}

extern "C" void kernel_launch(void* const* d_in, const int* in_sizes, int n_in,
                              void* d_out, int out_size, void* d_ws, size_t ws_size,
                              hipStream_t stream) {
    const float* traj = (const float*)d_in[0];
    const float* WihE = (const float*)d_in[1];
    const float* WhhE = (const float*)d_in[2];
    const float* bihE = (const float*)d_in[3];
    const float* bhhE = (const float*)d_in[4];
    const float* WihD = (const float*)d_in[5];
    const float* WhhD = (const float*)d_in[6];
    const float* bihD = (const float*)d_in[7];
    const float* bhhD = (const float*)d_in[8];
    const float* Wpos = (const float*)d_in[9];
    const float* bpos = (const float*)d_in[10];
    float* out = (float*)d_out;

    const int B = in_sizes[0] / (ENC_T * 2);   // 65536
    const int grid = B / 16;                   // 4096 workgroups, 16 rows each

    lstm_seq2seq<<<grid, 256, 0, stream>>>(traj, WihE, WhhE, bihE, bhhE,
                                           WihD, WhhD, bihD, bhhD, Wpos, bpos, out);
}